// Round 15
// baseline (1887.019 us; speedup 1.0000x reference)
//
#include <hip/hip_runtime.h>

#define SEQ   512
#define BATCH 32
#define EMBD  256
#define UNITS 512
#define G4    2048   // 4*UNITS
#define NW1   128    // K1 zx slot count (units/4), layout unchanged
#define NWD   32     // K2 workgroups per direction (2 rowgroups x 16 unitgroups)
#define UPW   32     // units per K2 workgroup
#define RPW   16     // batch rows per K2 workgroup
#define HSTR  520    // LDS h row stride in shorts
#define NTHR  512

typedef short  short8 __attribute__((ext_vector_type(8)));
typedef float  f32x4  __attribute__((ext_vector_type(4)));
typedef unsigned int u32x4 __attribute__((ext_vector_type(4)));
typedef unsigned int u32x2 __attribute__((ext_vector_type(2)));

static constexpr unsigned long long ZX2_OFF   = 0ull;
static constexpr unsigned long long ZX2_BYTES = 2ull * SEQ * NW1 * BATCH * 16 * 2; // 128 MiB
static constexpr unsigned long long HB_OFF    = ZX2_OFF + ZX2_BYTES;
static constexpr unsigned long long HB_BYTES  = 2ull * SEQ * BATCH * UNITS * 2;    // 32 MiB bf16
static constexpr unsigned long long FLG_OFF   = HB_OFF + HB_BYTES;
static constexpr unsigned long long FLG_BYTES = 4096;                              // claim flags
static constexpr unsigned long long SF_OFF    = FLG_OFF + FLG_BYTES;
static constexpr unsigned long long SF_BYTES  = 2ull * SEQ * NWD * 4;              // step flags

__device__ __forceinline__ unsigned short f2bf(float f) {
  unsigned int u = __float_as_uint(f);
  u = (u + 0x7FFFu + ((u >> 16) & 1u)) >> 16;
  return (unsigned short)u;
}
__device__ __forceinline__ float bf2f(unsigned short s) {
  return __uint_as_float(((unsigned int)s) << 16);
}
// sentinel = 0xFFFF (bf16 NaN). h = sigmoid*tanh, |h|<1 => never NaN pattern.
__device__ __forceinline__ unsigned sent2(unsigned w) {
  return (unsigned)(((w & 0xFFFFu) == 0xFFFFu) | ((w >> 16) == 0xFFFFu));
}
__device__ __forceinline__ unsigned chk4(u32x4 g) {
  return sent2(g[0]) | sent2(g[1]) | sent2(g[2]) | sent2(g[3]);
}

// -------------------- K1: zx = gather(emb,x) @ W + b  (fp32, bf16 out) -----
// unchanged (verified rounds 1-11)
__global__ __launch_bounds__(256)
void k_zx(const int* __restrict__ x, const float* __restrict__ emb,
          const float* __restrict__ Wf, const float* __restrict__ bf,
          const float* __restrict__ Wb, const float* __restrict__ bb,
          unsigned short* __restrict__ zx2)
{
  const int nb  = blockIdx.x;
  const int mb  = blockIdx.y;
  const int dir = blockIdx.z;
  const float* __restrict__ W    = dir ? Wb : Wf;
  const float* __restrict__ bias = dir ? bb : bf;
  const int tid = threadIdx.x;
  const int M0 = mb * 64, N0 = nb * 64;

  __shared__ __align__(16) float Ast[32][68];
  __shared__ __align__(16) float Bs [32][68];
  __shared__ int tok[64];

  if (tid < 64) {
    int m = M0 + tid;
    int t = m >> 5, b = m & 31;
    int s = dir ? (SEQ - 1 - t) : t;
    tok[tid] = x[b * SEQ + s];
  }

  float acc[4][4];
  #pragma unroll
  for (int r = 0; r < 4; ++r)
    #pragma unroll
    for (int c = 0; c < 4; ++c) acc[r][c] = 0.f;

  const int mq = tid >> 4, nq = tid & 15;

  for (int kb = 0; kb < 8; ++kb) {
    __syncthreads();
    {
      int m = tid >> 2, q = tid & 3;
      const float* src = emb + (size_t)tok[m] * EMBD + kb * 32 + q * 8;
      float4 v0 = *(const float4*)src;
      float4 v1 = *(const float4*)(src + 4);
      int k0 = q * 8;
      Ast[k0+0][m] = v0.x; Ast[k0+1][m] = v0.y; Ast[k0+2][m] = v0.z; Ast[k0+3][m] = v0.w;
      Ast[k0+4][m] = v1.x; Ast[k0+5][m] = v1.y; Ast[k0+6][m] = v1.z; Ast[k0+7][m] = v1.w;
    }
    {
      int k = tid >> 3, q = tid & 7;
      const float* src = W + (size_t)(kb*32 + k) * G4 + N0 + q * 8;
      float4 w0 = *(const float4*)src;
      float4 w1 = *(const float4*)(src + 4);
      *(float4*)&Bs[k][q*8]     = w0;
      *(float4*)&Bs[k][q*8 + 4] = w1;
    }
    __syncthreads();
    #pragma unroll 8
    for (int k = 0; k < 32; ++k) {
      float4 a  = *(const float4*)&Ast[k][mq*4];
      float4 bv = *(const float4*)&Bs[k][nq*4];
      acc[0][0] += a.x*bv.x; acc[0][1] += a.x*bv.y; acc[0][2] += a.x*bv.z; acc[0][3] += a.x*bv.w;
      acc[1][0] += a.y*bv.x; acc[1][1] += a.y*bv.y; acc[1][2] += a.y*bv.z; acc[1][3] += a.y*bv.w;
      acc[2][0] += a.z*bv.x; acc[2][1] += a.z*bv.y; acc[2][2] += a.z*bv.z; acc[2][3] += a.z*bv.w;
      acc[3][0] += a.w*bv.x; acc[3][1] += a.w*bv.y; acc[3][2] += a.w*bv.z; acc[3][3] += a.w*bv.w;
    }
  }

  float4 bs4 = *(const float4*)(bias + N0 + nq*4);
  const int g = N0 >> 9;
  const int u = (N0 & 511) + nq * 4;
  const int w = u >> 2;
  #pragma unroll
  for (int r = 0; r < 4; ++r) {
    int m = M0 + mq*4 + r;
    int t = m >> 5, b = m & 31;
    unsigned short p0 = f2bf(acc[r][0] + bs4.x);
    unsigned short p1 = f2bf(acc[r][1] + bs4.y);
    unsigned short p2 = f2bf(acc[r][2] + bs4.z);
    unsigned short p3 = f2bf(acc[r][3] + bs4.w);
    uint2 pk;
    pk.x = (unsigned)p0 | ((unsigned)p1 << 16);
    pk.y = (unsigned)p2 | ((unsigned)p3 << 16);
    size_t off = ((((size_t)dir*SEQ + t)*NW1 + w)*BATCH + b)*16 + g*4;
    *(uint2*)(zx2 + off) = pk;
  }
}

// -------------------- K2: recurrence, 16-row x 32-unit tiling ---------------
// slot = (dir, rg, ug): rg = rowgroup (16 rows), ug = unitgroup (32 units).
// 512 threads = 8 waves; wave ct (0..7) covers 16 cols = 4 gates x 4 units.
// Release-ordered flag: all waves drain publishes, barrier, then flag.
__global__ __launch_bounds__(NTHR, 2)
void k_rec2(const float* __restrict__ fh, const float* __restrict__ fc,
            const float* __restrict__ bh, const float* __restrict__ bc,
            const float* __restrict__ Uf, const float* __restrict__ Ub,
            const unsigned short* __restrict__ zx2,
            unsigned short* __restrict__ hring_all,
            int* __restrict__ claim, int* __restrict__ sflag,
            float* __restrict__ out)
{
  const int tid = threadIdx.x;
  __shared__ int s_slot, s_loc;

  // ---- self-placement: claim a slot preferring the dir's home XCD ----------
  if (tid == 0) {
    unsigned xcc;
    asm volatile("s_getreg_b32 %0, hwreg(HW_REG_XCC_ID)" : "=s"(xcc));
    int slot = -1;
    if (xcc < 2) {
      int base = (int)xcc * NWD;
      for (int i = 0; i < NWD && slot < 0; ++i)
        if (atomicCAS(&claim[base + i], 0, 1) == 0) slot = base + i;
    }
    if (slot < 0) {
      for (int sp = 0; sp < 96; ++sp) __builtin_amdgcn_s_sleep(8);
      for (int i = 0; i < 2 * NWD && slot < 0; ++i)
        if (atomicCAS(&claim[i], 0, 1) == 0) slot = i;
    }
    s_slot = slot;
    s_loc  = (slot >= 0 && (unsigned)(slot >> 5) == xcc) ? 1 : 0;
  }
  __syncthreads();
  const int slot = s_slot;
  if (slot < 0) return;
  const int loc = s_loc;
  const int dir = slot >> 5;
  const int rg  = (slot >> 4) & 1;   // rowgroup
  const int ug  = slot & 15;         // unitgroup
  const int u0  = ug * UPW;
  const int r0  = rg * RPW;
  const int l   = tid & 63;
  const int wid = tid >> 6;
  const int ct  = wid;               // unit-quad tile 0..7

  const float* __restrict__ U  = dir ? Ub : Uf;
  const float* __restrict__ h0 = dir ? bh : fh;
  const float* __restrict__ c0 = dir ? bc : fc;

  __shared__ __align__(16) unsigned short hs[RPW * HSTR];   // 16 rows x 512 k
  __shared__ __align__(16) float obuf[2][8][RPW][36];       // out stage

  unsigned short* __restrict__ hring = hring_all + (size_t)dir * SEQ * BATCH * UNITS;
  int* __restrict__ flg = sflag + (size_t)dir * SEQ * NWD;  // [t][rg*16+ug]
  const unsigned short* __restrict__ zxd =
      zx2 + ((size_t)dir * SEQ) * (NW1 * BATCH * 16);

  // ---- preload U slice as bf16 MFMA B-fragments, hi/lo split ---------------
  // B layout (16x16x32): lane l holds col=l&15, k=(l>>4)*8+j.
  // col -> gate (l&15)>>2, unit u0 + ct*4 + (l&3)
  const int gate = (l & 15) >> 2;
  const int krow = (l >> 4) * 8;
  const size_t gcol = (size_t)gate * 512 + u0 + ct * 4 + (l & 3);
  short8 uhi[16], ulo[16];
  #pragma unroll
  for (int s = 0; s < 16; ++s) {
    const float* up = U + (size_t)(s * 32 + krow) * G4 + gcol;
    short8 hi8, lo8;
    #pragma unroll
    for (int j = 0; j < 8; ++j) {
      float uv = up[(size_t)j * G4];
      unsigned short h16 = f2bf(uv);
      float rem = uv - bf2f(h16);
      hi8[j] = (short)h16;
      lo8[j] = (short)f2bf(rem);
    }
    uhi[s] = hi8; ulo[s] = lo8;
  }

  // ---- per-lane cell state (meaningful on gate-0 lanes) ---------------------
  float c_old[4];
  #pragma unroll
  for (int r = 0; r < 4; ++r) {
    int b_r = r0 + (l >> 4) * 4 + r;
    c_old[r] = c0[(size_t)b_r * UNITS + u0 + ct * 4 + (l & 3)];
  }

  // ---- stage h0 (fp32 -> bf16): 16 rows x 512 units -------------------------
  {
    int r = tid >> 5, cq = tid & 31;
    const float* src = h0 + (size_t)(r0 + r) * UNITS;
    #pragma unroll
    for (int i = 0; i < 2; ++i) {
      int c = i * 32 + cq;          // 16B group index 0..63
      float4 v0 = *(const float4*)(src + c * 8);
      float4 v1 = *(const float4*)(src + c * 8 + 4);
      short8 pk;
      pk[0]=(short)f2bf(v0.x); pk[1]=(short)f2bf(v0.y);
      pk[2]=(short)f2bf(v0.z); pk[3]=(short)f2bf(v0.w);
      pk[4]=(short)f2bf(v1.x); pk[5]=(short)f2bf(v1.y);
      pk[6]=(short)f2bf(v1.z); pk[7]=(short)f2bf(v1.w);
      *(short8*)(&hs[r * HSTR + c * 8]) = pk;
    }
  }
  __syncthreads();

  // per-lane constants
  const int arow  = l & 15;                        // A row within 16
  const unsigned short* hsrow = hs + arow * HSTR;
  const int agrp0 = l >> 4;
  const int sr = tid >> 5, scq = tid & 31;         // fetch/commit (32B/thread)
  unsigned short* const hs_dst = hs + sr * HSTR + scq * 16;
  const bool isg = gate == 2;                      // gate 2 = tanh
  const float An = isg ? 2.f : 1.f;
  const float Cn = isg ? -1.f : 0.f;
  const float Bn = isg ? -2.f : -1.f;
  const size_t ZXT = (size_t)NW1 * BATCH * 16;
  const size_t zbase = ((size_t)(8 * ug + ct) * BATCH + r0 + (l >> 4) * 4) * 16
                       + gate * 4 + (l & 3);
  // burst mapping: j = tid>>6, row = (tid>>2)&15, uq = tid&3 (8 floats each)
  const int bj = tid >> 6, brow = (tid >> 2) & 15, buq = tid & 3;

  // zx for t=0 preloaded
  unsigned short zx_cur[4];
  #pragma unroll
  for (int r = 0; r < 4; ++r) zx_cur[r] = zxd[zbase + r * 16];

  for (int t = 0; t < SEQ; ++t) {
    if (t > 0) {
      // ---- flag poll: wave 0 only, 16 producer flags -------------------------
      if (wid == 0) {
        const int* fpl = flg + (size_t)(t - 1) * NWD + rg * 16 + (l & 15);
        unsigned v; int guard = 0;
        for (;;) {
          if ((guard & 3) == 3)
            asm volatile("global_load_dword %0, %1, off sc0 sc1\n\ts_waitcnt vmcnt(0)"
                         : "=v"(v) : "v"(fpl) : "memory");
          else
            asm volatile("global_load_dword %0, %1, off sc0\n\ts_waitcnt vmcnt(0)"
                         : "=v"(v) : "v"(fpl) : "memory");
          __builtin_amdgcn_sched_barrier(0);
          if (__ballot(v != 0) == ~0ull || ++guard >= (1 << 20)) break;
          __builtin_amdgcn_s_sleep(1);
        }
      }
      __syncthreads();
      // ---- data fetch: 16 KB/WG (sentinel = correctness net) -----------------
      const unsigned short* src =
          hring + ((size_t)(t - 1) * BATCH + r0 + sr) * UNITS + scq * 16;
      u32x4 g0, g1;
      asm volatile("global_load_dwordx4 %0, %1, off sc0"           : "=&v"(g0) : "v"(src) : "memory");
      asm volatile("global_load_dwordx4 %0, %1, off offset:16 sc0" : "=&v"(g1) : "v"(src) : "memory");
      asm volatile("s_waitcnt vmcnt(0)" : "+v"(g0), "+v"(g1));
      __builtin_amdgcn_sched_barrier(0);
      unsigned b0 = chk4(g0), b1 = chk4(g1);
      int guard = 0;
      while ((b0 | b1) && ++guard < (1 << 20)) {
        __builtin_amdgcn_s_sleep(1);
        if (guard & 1) {  // alternate coherence level to defeat stale L2 lines
          if (b0) asm volatile("global_load_dwordx4 %0, %1, off sc0 sc1"           : "=&v"(g0) : "v"(src) : "memory");
          if (b1) asm volatile("global_load_dwordx4 %0, %1, off offset:16 sc0 sc1" : "=&v"(g1) : "v"(src) : "memory");
        } else {
          if (b0) asm volatile("global_load_dwordx4 %0, %1, off sc0"           : "=&v"(g0) : "v"(src) : "memory");
          if (b1) asm volatile("global_load_dwordx4 %0, %1, off offset:16 sc0" : "=&v"(g1) : "v"(src) : "memory");
        }
        asm volatile("s_waitcnt vmcnt(0)" : "+v"(g0), "+v"(g1));
        __builtin_amdgcn_sched_barrier(0);
        b0 = chk4(g0); b1 = chk4(g1);
      }
      // commit to LDS
      *(u32x4*)(hs_dst    ) = g0;
      *(u32x4*)(hs_dst + 8) = g1;

      // ---- every 8th step: burst staged out rows (acks hide under MFMA) ------
      if ((t & 7) == 0 && t >= 8) {
        int tb = t - 8, bank = ((t - 8) >> 3) & 1;
        int tj = tb + bj;
        int sidx = dir ? (SEQ - 1 - tj) : tj;
        const f32x4* sp = (const f32x4*)&obuf[bank][bj][brow][buq * 8];
        f32x4 v0 = sp[0];
        f32x4 v1 = sp[1];
        float* dst = out + ((size_t)(r0 + brow) * SEQ + sidx) * 1024 + dir * 512 + u0 + buq * 8;
        __builtin_nontemporal_store(v0, (f32x4*)dst);
        __builtin_nontemporal_store(v1, (f32x4*)(dst + 4));
      }
      __builtin_amdgcn_sched_barrier(0);
    }

    // ---- zx(t+1) prefetch (retires under MFMA+gates before publish drain) ---
    unsigned short zx_nxt[4] = {0, 0, 0, 0};
    if (t + 1 < SEQ) {
      #pragma unroll
      for (int r = 0; r < 4; ++r)
        zx_nxt[r] = zxd[(size_t)(t + 1) * ZXT + zbase + r * 16];
    }
    __builtin_amdgcn_sched_barrier(0);
    if (t > 0) __syncthreads();

    // ---- z = h · (Uhi + Ulo) via MFMA, split accumulators ----
    f32x4 accA = {0.f, 0.f, 0.f, 0.f};
    f32x4 accB = {0.f, 0.f, 0.f, 0.f};
    #pragma unroll
    for (int s = 0; s < 16; ++s) {
      short8 a = *(const short8*)(hsrow + (4 * s + agrp0) * 8);
      accA = __builtin_amdgcn_mfma_f32_16x16x32_bf16(a, uhi[s], accA, 0, 0, 0);
      accB = __builtin_amdgcn_mfma_f32_16x16x32_bf16(a, ulo[s], accB, 0, 0, 0);
    }

    // ---- in-register gates: lanes l, l^4, l^8 hold the 4 gates of (b,u) ----
    float vv[4];
    #pragma unroll
    for (int r = 0; r < 4; ++r) {
      float z = accA[r] + accB[r] + bf2f(zx_cur[r]);
      float e = __expf(Bn * z);
      vv[r] = An * __builtin_amdgcn_rcpf(1.f + e) + Cn;   // sigma or tanh
    }
    float hn[4], cn[4];
    unsigned pk0[4], pk1[4];
    #pragma unroll
    for (int r = 0; r < 4; ++r) {
      float wv = __shfl_xor(vv[r], 8);
      float x1 = __shfl_xor(vv[r], 4);
      float x2 = __shfl_xor(wv,    4);
      cn[r] = x1 * c_old[r] + vv[r] * wv;
      c_old[r] = cn[r];
      float e2 = __expf(-2.f * cn[r]);
      float th = 2.f * __builtin_amdgcn_rcpf(1.f + e2) - 1.f;
      hn[r] = x2 * th;
      unsigned hb = (unsigned)f2bf(hn[r]);
      unsigned d  = (hb & 0xFFFFu) | (__shfl_xor((int)hb, 1) << 16);
      unsigned d2 = (unsigned)__shfl_xor((int)d, 2);
      pk0[r] = d; pk1[r] = d2;
    }

    // ---- publish h, RELEASE-ORDERED flag ------------------------------------
    if (t < SEQ - 1) {
      if ((l & 15) == 0) {
        #pragma unroll
        for (int r = 0; r < 4; ++r) {
          int b_r = r0 + (l >> 4) * 4 + r;
          unsigned short* dst = hring + ((size_t)t * BATCH + b_r) * UNITS + u0 + ct * 4;
          u32x2 pk; pk[0] = pk0[r]; pk[1] = pk1[r];
          if (loc)
            asm volatile("global_store_dwordx2 %0, %1, off sc0"
                         :: "v"(dst), "v"(pk) : "memory");
          else
            asm volatile("global_store_dwordx2 %0, %1, off sc0 sc1"
                         :: "v"(dst), "v"(pk) : "memory");
        }
      }
      // every wave drains its own publishes; barrier; then flag -> no races
      asm volatile("s_waitcnt vmcnt(0)" ::: "memory");
      __syncthreads();
      if (tid == 0) {
        int* fdst = flg + (size_t)t * NWD + rg * 16 + ug;
        unsigned one = 1u;
        if (loc)
          asm volatile("global_store_dword %0, %1, off sc0"
                       :: "v"(fdst), "v"(one) : "memory");
        else
          asm volatile("global_store_dword %0, %1, off sc0 sc1"
                       :: "v"(fdst), "v"(one) : "memory");
      }
    }
    __builtin_amdgcn_sched_barrier(0);

    // ---- stage out rows to LDS (burst-written every 8 steps) ----------------
    if ((l & 15) < 4) {
      int jj = t & 7, bank = (t >> 3) & 1;
      #pragma unroll
      for (int r = 0; r < 4; ++r)
        obuf[bank][jj][(l >> 4) * 4 + r][ct * 4 + (l & 3)] = hn[r];
      if (t == SEQ - 1) {
        size_t base = (size_t)BATCH * SEQ * 1024;
        #pragma unroll
        for (int r = 0; r < 4; ++r) {
          int b_r = r0 + (l >> 4) * 4 + r;
          size_t o1 = base + (size_t)(2*dir  ) * BATCH * UNITS + (size_t)b_r * UNITS + u0 + ct * 4 + (l & 3);
          size_t o2 = base + (size_t)(2*dir+1) * BATCH * UNITS + (size_t)b_r * UNITS + u0 + ct * 4 + (l & 3);
          __builtin_nontemporal_store(hn[r], &out[o1]);
          __builtin_nontemporal_store(cn[r], &out[o2]);
        }
      }
    }

    #pragma unroll
    for (int r = 0; r < 4; ++r) zx_cur[r] = zx_nxt[r];
  }

  // ---- epilogue: burst the final 8 staged steps (t = 504..511) --------------
  __syncthreads();
  {
    int tb = SEQ - 8, bank = ((SEQ - 8) >> 3) & 1;
    int tj = tb + bj;
    int sidx = dir ? (SEQ - 1 - tj) : tj;
    const f32x4* sp = (const f32x4*)&obuf[bank][bj][brow][buq * 8];
    f32x4 v0 = sp[0];
    f32x4 v1 = sp[1];
    float* dst = out + ((size_t)(r0 + brow) * SEQ + sidx) * 1024 + dir * 512 + u0 + buq * 8;
    __builtin_nontemporal_store(v0, (f32x4*)dst);
    __builtin_nontemporal_store(v1, (f32x4*)(dst + 4));
  }
}

// -------------------- launch ----------------------------------------------
extern "C" void kernel_launch(void* const* d_in, const int* in_sizes, int n_in,
                              void* d_out, int out_size, void* d_ws, size_t ws_size,
                              hipStream_t stream)
{
  const int*   x   = (const int*)  d_in[0];
  const float* fh  = (const float*)d_in[1];
  const float* fc  = (const float*)d_in[2];
  const float* bh  = (const float*)d_in[3];
  const float* bc  = (const float*)d_in[4];
  const float* emb = (const float*)d_in[5];
  const float* Wf  = (const float*)d_in[6];
  const float* Uf  = (const float*)d_in[7];
  const float* bf  = (const float*)d_in[8];
  const float* Wb  = (const float*)d_in[9];
  const float* Ub  = (const float*)d_in[10];
  const float* bb  = (const float*)d_in[11];
  float* out = (float*)d_out;

  if (ws_size < SF_OFF + SF_BYTES) return;

  unsigned short* zx2   = (unsigned short*)((char*)d_ws + ZX2_OFF);
  unsigned short* hring = (unsigned short*)((char*)d_ws + HB_OFF);
  int*            claim = (int*)((char*)d_ws + FLG_OFF);
  int*            sflag = (int*)((char*)d_ws + SF_OFF);

  // sentinel-fill h ring (0xFFFF = not ready) + zero claim/step flags
  hipMemsetAsync(hring, 0xFF, HB_BYTES, stream);
  hipMemsetAsync(claim, 0, FLG_BYTES + SF_BYTES, stream);
  k_zx  <<<dim3(32, 256, 2), 256, 0, stream>>>(x, emb, Wf, bf, Wb, bb, zx2);
  k_rec2<<<dim3(256), NTHR, 0, stream>>>(fh, fc, bh, bc, Uf, Ub, zx2, hring, claim, sflag, out);
}

// Round 16
// 1879.642 us; speedup vs baseline: 1.0039x; 1.0039x over previous
//
#include <hip/hip_runtime.h>

#define SEQ   512
#define BATCH 32
#define EMBD  256
#define UNITS 512
#define G4    2048   // 4*UNITS
#define NW1   128    // K1 zx slot count (units/4), layout unchanged
#define NWD   32     // K2 workgroups per direction (2 rowgroups x 16 unitgroups)
#define UPW   32     // units per K2 workgroup
#define RPW   16     // batch rows per K2 workgroup
#define HSTR  520    // LDS h row stride in shorts
#define NTHR  512

typedef short  short8 __attribute__((ext_vector_type(8)));
typedef float  f32x4  __attribute__((ext_vector_type(4)));
typedef unsigned int u32x4 __attribute__((ext_vector_type(4)));
typedef unsigned int u32x2 __attribute__((ext_vector_type(2)));

static constexpr unsigned long long ZX2_OFF   = 0ull;
static constexpr unsigned long long ZX2_BYTES = 2ull * SEQ * NW1 * BATCH * 16 * 2; // 128 MiB
static constexpr unsigned long long HB_OFF    = ZX2_OFF + ZX2_BYTES;
static constexpr unsigned long long HB_BYTES  = 2ull * SEQ * BATCH * UNITS * 2;    // 32 MiB bf16
static constexpr unsigned long long FLG_OFF   = HB_OFF + HB_BYTES;
static constexpr unsigned long long FLG_BYTES = 4096;                              // claim flags
static constexpr unsigned long long SF_OFF    = FLG_OFF + FLG_BYTES;
static constexpr unsigned long long SF_BYTES  = 2ull * SEQ * NWD * 4;              // step flags

__device__ __forceinline__ unsigned short f2bf(float f) {
  unsigned int u = __float_as_uint(f);
  u = (u + 0x7FFFu + ((u >> 16) & 1u)) >> 16;
  return (unsigned short)u;
}
__device__ __forceinline__ float bf2f(unsigned short s) {
  return __uint_as_float(((unsigned int)s) << 16);
}
// sentinel = 0xFFFF (bf16 NaN). h = sigmoid*tanh, |h|<1 => never NaN pattern.
__device__ __forceinline__ unsigned sent2(unsigned w) {
  return (unsigned)(((w & 0xFFFFu) == 0xFFFFu) | ((w >> 16) == 0xFFFFu));
}
__device__ __forceinline__ unsigned chk4(u32x4 g) {
  return sent2(g[0]) | sent2(g[1]) | sent2(g[2]) | sent2(g[3]);
}

// -------------------- K1: zx = gather(emb,x) @ W + b  (fp32, bf16 out) -----
// unchanged (verified rounds 1-11)
__global__ __launch_bounds__(256)
void k_zx(const int* __restrict__ x, const float* __restrict__ emb,
          const float* __restrict__ Wf, const float* __restrict__ bf,
          const float* __restrict__ Wb, const float* __restrict__ bb,
          unsigned short* __restrict__ zx2)
{
  const int nb  = blockIdx.x;
  const int mb  = blockIdx.y;
  const int dir = blockIdx.z;
  const float* __restrict__ W    = dir ? Wb : Wf;
  const float* __restrict__ bias = dir ? bb : bf;
  const int tid = threadIdx.x;
  const int M0 = mb * 64, N0 = nb * 64;

  __shared__ __align__(16) float Ast[32][68];
  __shared__ __align__(16) float Bs [32][68];
  __shared__ int tok[64];

  if (tid < 64) {
    int m = M0 + tid;
    int t = m >> 5, b = m & 31;
    int s = dir ? (SEQ - 1 - t) : t;
    tok[tid] = x[b * SEQ + s];
  }

  float acc[4][4];
  #pragma unroll
  for (int r = 0; r < 4; ++r)
    #pragma unroll
    for (int c = 0; c < 4; ++c) acc[r][c] = 0.f;

  const int mq = tid >> 4, nq = tid & 15;

  for (int kb = 0; kb < 8; ++kb) {
    __syncthreads();
    {
      int m = tid >> 2, q = tid & 3;
      const float* src = emb + (size_t)tok[m] * EMBD + kb * 32 + q * 8;
      float4 v0 = *(const float4*)src;
      float4 v1 = *(const float4*)(src + 4);
      int k0 = q * 8;
      Ast[k0+0][m] = v0.x; Ast[k0+1][m] = v0.y; Ast[k0+2][m] = v0.z; Ast[k0+3][m] = v0.w;
      Ast[k0+4][m] = v1.x; Ast[k0+5][m] = v1.y; Ast[k0+6][m] = v1.z; Ast[k0+7][m] = v1.w;
    }
    {
      int k = tid >> 3, q = tid & 7;
      const float* src = W + (size_t)(kb*32 + k) * G4 + N0 + q * 8;
      float4 w0 = *(const float4*)src;
      float4 w1 = *(const float4*)(src + 4);
      *(float4*)&Bs[k][q*8]     = w0;
      *(float4*)&Bs[k][q*8 + 4] = w1;
    }
    __syncthreads();
    #pragma unroll 8
    for (int k = 0; k < 32; ++k) {
      float4 a  = *(const float4*)&Ast[k][mq*4];
      float4 bv = *(const float4*)&Bs[k][nq*4];
      acc[0][0] += a.x*bv.x; acc[0][1] += a.x*bv.y; acc[0][2] += a.x*bv.z; acc[0][3] += a.x*bv.w;
      acc[1][0] += a.y*bv.x; acc[1][1] += a.y*bv.y; acc[1][2] += a.y*bv.z; acc[1][3] += a.y*bv.w;
      acc[2][0] += a.z*bv.x; acc[2][1] += a.z*bv.y; acc[2][2] += a.z*bv.z; acc[2][3] += a.z*bv.w;
      acc[3][0] += a.w*bv.x; acc[3][1] += a.w*bv.y; acc[3][2] += a.w*bv.z; acc[3][3] += a.w*bv.w;
    }
  }

  float4 bs4 = *(const float4*)(bias + N0 + nq*4);
  const int g = N0 >> 9;
  const int u = (N0 & 511) + nq * 4;
  const int w = u >> 2;
  #pragma unroll
  for (int r = 0; r < 4; ++r) {
    int m = M0 + mq*4 + r;
    int t = m >> 5, b = m & 31;
    unsigned short p0 = f2bf(acc[r][0] + bs4.x);
    unsigned short p1 = f2bf(acc[r][1] + bs4.y);
    unsigned short p2 = f2bf(acc[r][2] + bs4.z);
    unsigned short p3 = f2bf(acc[r][3] + bs4.w);
    uint2 pk;
    pk.x = (unsigned)p0 | ((unsigned)p1 << 16);
    pk.y = (unsigned)p2 | ((unsigned)p3 << 16);
    size_t off = ((((size_t)dir*SEQ + t)*NW1 + w)*BATCH + b)*16 + g*4;
    *(uint2*)(zx2 + off) = pk;
  }
}

// -------------------- K2: recurrence, 16-row x 32-unit tiling ---------------
// slot = (dir, rg, ug): rg = rowgroup (16 rows), ug = unitgroup (32 units).
// 512 threads = 8 waves; wave ct (0..7) covers 16 cols = 4 gates x 4 units.
// Release-ordered flag: all waves drain publishes, barrier, then flag.
__global__ __launch_bounds__(NTHR, 2)
void k_rec2(const float* __restrict__ fh, const float* __restrict__ fc,
            const float* __restrict__ bh, const float* __restrict__ bc,
            const float* __restrict__ Uf, const float* __restrict__ Ub,
            const unsigned short* __restrict__ zx2,
            unsigned short* __restrict__ hring_all,
            int* __restrict__ claim, int* __restrict__ sflag,
            float* __restrict__ out)
{
  const int tid = threadIdx.x;
  __shared__ int s_slot, s_loc;

  // ---- self-placement: claim a slot preferring the dir's home XCD ----------
  if (tid == 0) {
    unsigned xcc;
    asm volatile("s_getreg_b32 %0, hwreg(HW_REG_XCC_ID)" : "=s"(xcc));
    int slot = -1;
    if (xcc < 2) {
      int base = (int)xcc * NWD;
      for (int i = 0; i < NWD && slot < 0; ++i)
        if (atomicCAS(&claim[base + i], 0, 1) == 0) slot = base + i;
    }
    if (slot < 0) {
      for (int sp = 0; sp < 96; ++sp) __builtin_amdgcn_s_sleep(8);
      for (int i = 0; i < 2 * NWD && slot < 0; ++i)
        if (atomicCAS(&claim[i], 0, 1) == 0) slot = i;
    }
    s_slot = slot;
    s_loc  = (slot >= 0 && (unsigned)(slot >> 5) == xcc) ? 1 : 0;
  }
  __syncthreads();
  const int slot = s_slot;
  if (slot < 0) return;
  const int loc = s_loc;
  const int dir = slot >> 5;
  const int rg  = (slot >> 4) & 1;   // rowgroup
  const int ug  = slot & 15;         // unitgroup
  const int u0  = ug * UPW;
  const int r0  = rg * RPW;
  const int l   = tid & 63;
  const int wid = tid >> 6;
  const int ct  = wid;               // unit-quad tile 0..7

  const float* __restrict__ U  = dir ? Ub : Uf;
  const float* __restrict__ h0 = dir ? bh : fh;
  const float* __restrict__ c0 = dir ? bc : fc;

  __shared__ __align__(16) unsigned short hs[RPW * HSTR];   // 16 rows x 512 k
  __shared__ __align__(16) float obuf[2][8][RPW][36];       // out stage

  unsigned short* __restrict__ hring = hring_all + (size_t)dir * SEQ * BATCH * UNITS;
  int* __restrict__ flg = sflag + (size_t)dir * SEQ * NWD;  // [t][rg*16+ug]
  const unsigned short* __restrict__ zxd =
      zx2 + ((size_t)dir * SEQ) * (NW1 * BATCH * 16);

  // ---- preload U slice as bf16 MFMA B-fragments, hi/lo split ---------------
  // B layout (16x16x32): lane l holds col=l&15, k=(l>>4)*8+j.
  // col -> gate (l&15)>>2, unit u0 + ct*4 + (l&3)
  const int gate = (l & 15) >> 2;
  const int krow = (l >> 4) * 8;
  const size_t gcol = (size_t)gate * 512 + u0 + ct * 4 + (l & 3);
  short8 uhi[16], ulo[16];
  #pragma unroll
  for (int s = 0; s < 16; ++s) {
    const float* up = U + (size_t)(s * 32 + krow) * G4 + gcol;
    short8 hi8, lo8;
    #pragma unroll
    for (int j = 0; j < 8; ++j) {
      float uv = up[(size_t)j * G4];
      unsigned short h16 = f2bf(uv);
      float rem = uv - bf2f(h16);
      hi8[j] = (short)h16;
      lo8[j] = (short)f2bf(rem);
    }
    uhi[s] = hi8; ulo[s] = lo8;
  }

  // ---- per-lane cell state (meaningful on gate-0 lanes) ---------------------
  float c_old[4];
  #pragma unroll
  for (int r = 0; r < 4; ++r) {
    int b_r = r0 + (l >> 4) * 4 + r;
    c_old[r] = c0[(size_t)b_r * UNITS + u0 + ct * 4 + (l & 3)];
  }

  // ---- stage h0 (fp32 -> bf16): 16 rows x 512 units -------------------------
  {
    int r = tid >> 5, cq = tid & 31;
    const float* src = h0 + (size_t)(r0 + r) * UNITS;
    #pragma unroll
    for (int i = 0; i < 2; ++i) {
      int c = i * 32 + cq;          // 16B group index 0..63
      float4 v0 = *(const float4*)(src + c * 8);
      float4 v1 = *(const float4*)(src + c * 8 + 4);
      short8 pk;
      pk[0]=(short)f2bf(v0.x); pk[1]=(short)f2bf(v0.y);
      pk[2]=(short)f2bf(v0.z); pk[3]=(short)f2bf(v0.w);
      pk[4]=(short)f2bf(v1.x); pk[5]=(short)f2bf(v1.y);
      pk[6]=(short)f2bf(v1.z); pk[7]=(short)f2bf(v1.w);
      *(short8*)(&hs[r * HSTR + c * 8]) = pk;
    }
  }
  __syncthreads();

  // per-lane constants
  const int arow  = l & 15;                        // A row within 16
  const unsigned short* hsrow = hs + arow * HSTR;
  const int agrp0 = l >> 4;
  const int sr = tid >> 5, scq = tid & 31;         // fetch/commit (32B/thread)
  unsigned short* const hs_dst = hs + sr * HSTR + scq * 16;
  const bool isg = gate == 2;                      // gate 2 = tanh
  const float An = isg ? 2.f : 1.f;
  const float Cn = isg ? -1.f : 0.f;
  const float Bn = isg ? -2.f : -1.f;
  const size_t ZXT = (size_t)NW1 * BATCH * 16;
  const size_t zbase = ((size_t)(8 * ug + ct) * BATCH + r0 + (l >> 4) * 4) * 16
                       + gate * 4 + (l & 3);
  // burst mapping: j = tid>>6, row = (tid>>2)&15, uq = tid&3 (8 floats each)
  const int bj = tid >> 6, brow = (tid >> 2) & 15, buq = tid & 3;

  // zx for t=0 preloaded
  unsigned short zx_cur[4];
  #pragma unroll
  for (int r = 0; r < 4; ++r) zx_cur[r] = zxd[zbase + r * 16];

  for (int t = 0; t < SEQ; ++t) {
    if (t > 0) {
      // ---- flag poll: wave 0 only, 16 producer flags -------------------------
      if (wid == 0) {
        const int* fpl = flg + (size_t)(t - 1) * NWD + rg * 16 + (l & 15);
        unsigned v; int guard = 0;
        for (;;) {
          if ((guard & 3) == 3)
            asm volatile("global_load_dword %0, %1, off sc0 sc1\n\ts_waitcnt vmcnt(0)"
                         : "=v"(v) : "v"(fpl) : "memory");
          else
            asm volatile("global_load_dword %0, %1, off sc0\n\ts_waitcnt vmcnt(0)"
                         : "=v"(v) : "v"(fpl) : "memory");
          __builtin_amdgcn_sched_barrier(0);
          if (__ballot(v != 0) == ~0ull || ++guard >= (1 << 20)) break;
          __builtin_amdgcn_s_sleep(1);
        }
      }
      __syncthreads();
      // ---- data fetch: 16 KB/WG (sentinel = correctness net) -----------------
      const unsigned short* src =
          hring + ((size_t)(t - 1) * BATCH + r0 + sr) * UNITS + scq * 16;
      u32x4 g0, g1;
      asm volatile("global_load_dwordx4 %0, %1, off sc0"           : "=&v"(g0) : "v"(src) : "memory");
      asm volatile("global_load_dwordx4 %0, %1, off offset:16 sc0" : "=&v"(g1) : "v"(src) : "memory");
      asm volatile("s_waitcnt vmcnt(0)" : "+v"(g0), "+v"(g1));
      __builtin_amdgcn_sched_barrier(0);
      unsigned b0 = chk4(g0), b1 = chk4(g1);
      int guard = 0;
      while ((b0 | b1) && ++guard < (1 << 20)) {
        __builtin_amdgcn_s_sleep(1);
        if (guard & 1) {  // alternate coherence level to defeat stale L2 lines
          if (b0) asm volatile("global_load_dwordx4 %0, %1, off sc0 sc1"           : "=&v"(g0) : "v"(src) : "memory");
          if (b1) asm volatile("global_load_dwordx4 %0, %1, off offset:16 sc0 sc1" : "=&v"(g1) : "v"(src) : "memory");
        } else {
          if (b0) asm volatile("global_load_dwordx4 %0, %1, off sc0"           : "=&v"(g0) : "v"(src) : "memory");
          if (b1) asm volatile("global_load_dwordx4 %0, %1, off offset:16 sc0" : "=&v"(g1) : "v"(src) : "memory");
        }
        asm volatile("s_waitcnt vmcnt(0)" : "+v"(g0), "+v"(g1));
        __builtin_amdgcn_sched_barrier(0);
        b0 = chk4(g0); b1 = chk4(g1);
      }
      // commit to LDS
      *(u32x4*)(hs_dst    ) = g0;
      *(u32x4*)(hs_dst + 8) = g1;

      // ---- every 8th step: burst staged out rows (acks hide under MFMA) ------
      if ((t & 7) == 0 && t >= 8) {
        int tb = t - 8, bank = ((t - 8) >> 3) & 1;
        int tj = tb + bj;
        int sidx = dir ? (SEQ - 1 - tj) : tj;
        const f32x4* sp = (const f32x4*)&obuf[bank][bj][brow][buq * 8];
        f32x4 v0 = sp[0];
        f32x4 v1 = sp[1];
        float* dst = out + ((size_t)(r0 + brow) * SEQ + sidx) * 1024 + dir * 512 + u0 + buq * 8;
        __builtin_nontemporal_store(v0, (f32x4*)dst);
        __builtin_nontemporal_store(v1, (f32x4*)(dst + 4));
      }
      __builtin_amdgcn_sched_barrier(0);
    }

    // ---- zx(t+1) prefetch (retires under MFMA+gates before publish drain) ---
    unsigned short zx_nxt[4] = {0, 0, 0, 0};
    if (t + 1 < SEQ) {
      #pragma unroll
      for (int r = 0; r < 4; ++r)
        zx_nxt[r] = zxd[(size_t)(t + 1) * ZXT + zbase + r * 16];
    }
    __builtin_amdgcn_sched_barrier(0);
    if (t > 0) __syncthreads();

    // ---- z = h · (Uhi + Ulo) via MFMA, split accumulators ----
    f32x4 accA = {0.f, 0.f, 0.f, 0.f};
    f32x4 accB = {0.f, 0.f, 0.f, 0.f};
    #pragma unroll
    for (int s = 0; s < 16; ++s) {
      short8 a = *(const short8*)(hsrow + (4 * s + agrp0) * 8);
      accA = __builtin_amdgcn_mfma_f32_16x16x32_bf16(a, uhi[s], accA, 0, 0, 0);
      accB = __builtin_amdgcn_mfma_f32_16x16x32_bf16(a, ulo[s], accB, 0, 0, 0);
    }

    // ---- in-register gates: lanes l, l^4, l^8 hold the 4 gates of (b,u) ----
    float vv[4];
    #pragma unroll
    for (int r = 0; r < 4; ++r) {
      float z = accA[r] + accB[r] + bf2f(zx_cur[r]);
      float e = __expf(Bn * z);
      vv[r] = An * __builtin_amdgcn_rcpf(1.f + e) + Cn;   // sigma or tanh
    }
    float hn[4], cn[4];
    unsigned pk0[4], pk1[4];
    #pragma unroll
    for (int r = 0; r < 4; ++r) {
      float wv = __shfl_xor(vv[r], 8);
      float x1 = __shfl_xor(vv[r], 4);
      float x2 = __shfl_xor(wv,    4);
      cn[r] = x1 * c_old[r] + vv[r] * wv;
      c_old[r] = cn[r];
      float e2 = __expf(-2.f * cn[r]);
      float th = 2.f * __builtin_amdgcn_rcpf(1.f + e2) - 1.f;
      hn[r] = x2 * th;
      unsigned hb = (unsigned)f2bf(hn[r]);
      unsigned d  = (hb & 0xFFFFu) | (__shfl_xor((int)hb, 1) << 16);
      unsigned d2 = (unsigned)__shfl_xor((int)d, 2);
      pk0[r] = d; pk1[r] = d2;
    }

    // ---- publish h, RELEASE-ORDERED flag ------------------------------------
    if (t < SEQ - 1) {
      if ((l & 15) == 0) {
        #pragma unroll
        for (int r = 0; r < 4; ++r) {
          int b_r = r0 + (l >> 4) * 4 + r;
          unsigned short* dst = hring + ((size_t)t * BATCH + b_r) * UNITS + u0 + ct * 4;
          u32x2 pk; pk[0] = pk0[r]; pk[1] = pk1[r];
          if (loc)
            asm volatile("global_store_dwordx2 %0, %1, off sc0"
                         :: "v"(dst), "v"(pk) : "memory");
          else
            asm volatile("global_store_dwordx2 %0, %1, off sc0 sc1"
                         :: "v"(dst), "v"(pk) : "memory");
        }
      }
      // every wave drains its own publishes; barrier; then flag -> no races
      asm volatile("s_waitcnt vmcnt(0)" ::: "memory");
      __syncthreads();
      if (tid == 0) {
        int* fdst = flg + (size_t)t * NWD + rg * 16 + ug;
        unsigned one = 1u;
        if (loc)
          asm volatile("global_store_dword %0, %1, off sc0"
                       :: "v"(fdst), "v"(one) : "memory");
        else
          asm volatile("global_store_dword %0, %1, off sc0 sc1"
                       :: "v"(fdst), "v"(one) : "memory");
      }
    }
    __builtin_amdgcn_sched_barrier(0);

    // ---- stage out rows to LDS (burst-written every 8 steps) ----------------
    if ((l & 15) < 4) {
      int jj = t & 7, bank = (t >> 3) & 1;
      #pragma unroll
      for (int r = 0; r < 4; ++r)
        obuf[bank][jj][(l >> 4) * 4 + r][ct * 4 + (l & 3)] = hn[r];
      if (t == SEQ - 1) {
        size_t base = (size_t)BATCH * SEQ * 1024;
        #pragma unroll
        for (int r = 0; r < 4; ++r) {
          int b_r = r0 + (l >> 4) * 4 + r;
          size_t o1 = base + (size_t)(2*dir  ) * BATCH * UNITS + (size_t)b_r * UNITS + u0 + ct * 4 + (l & 3);
          size_t o2 = base + (size_t)(2*dir+1) * BATCH * UNITS + (size_t)b_r * UNITS + u0 + ct * 4 + (l & 3);
          __builtin_nontemporal_store(hn[r], &out[o1]);
          __builtin_nontemporal_store(cn[r], &out[o2]);
        }
      }
    }

    #pragma unroll
    for (int r = 0; r < 4; ++r) zx_cur[r] = zx_nxt[r];
  }

  // ---- epilogue: burst the final 8 staged steps (t = 504..511) --------------
  __syncthreads();
  {
    int tb = SEQ - 8, bank = ((SEQ - 8) >> 3) & 1;
    int tj = tb + bj;
    int sidx = dir ? (SEQ - 1 - tj) : tj;
    const f32x4* sp = (const f32x4*)&obuf[bank][bj][brow][buq * 8];
    f32x4 v0 = sp[0];
    f32x4 v1 = sp[1];
    float* dst = out + ((size_t)(r0 + brow) * SEQ + sidx) * 1024 + dir * 512 + u0 + buq * 8;
    __builtin_nontemporal_store(v0, (f32x4*)dst);
    __builtin_nontemporal_store(v1, (f32x4*)(dst + 4));
  }
}

// -------------------- launch ----------------------------------------------
extern "C" void kernel_launch(void* const* d_in, const int* in_sizes, int n_in,
                              void* d_out, int out_size, void* d_ws, size_t ws_size,
                              hipStream_t stream)
{
  const int*   x   = (const int*)  d_in[0];
  const float* fh  = (const float*)d_in[1];
  const float* fc  = (const float*)d_in[2];
  const float* bh  = (const float*)d_in[3];
  const float* bc  = (const float*)d_in[4];
  const float* emb = (const float*)d_in[5];
  const float* Wf  = (const float*)d_in[6];
  const float* Uf  = (const float*)d_in[7];
  const float* bf  = (const float*)d_in[8];
  const float* Wb  = (const float*)d_in[9];
  const float* Ub  = (const float*)d_in[10];
  const float* bb  = (const float*)d_in[11];
  float* out = (float*)d_out;

  if (ws_size < SF_OFF + SF_BYTES) return;

  unsigned short* zx2   = (unsigned short*)((char*)d_ws + ZX2_OFF);
  unsigned short* hring = (unsigned short*)((char*)d_ws + HB_OFF);
  int*            claim = (int*)((char*)d_ws + FLG_OFF);
  int*            sflag = (int*)((char*)d_ws + SF_OFF);

  // sentinel-fill h ring (0xFFFF = not ready) + zero claim/step flags
  hipMemsetAsync(hring, 0xFF, HB_BYTES, stream);
  hipMemsetAsync(claim, 0, FLG_BYTES + SF_BYTES, stream);
  k_zx  <<<dim3(32, 256, 2), 256, 0, stream>>>(x, emb, Wf, bf, Wb, bb, zx2);
  k_rec2<<<dim3(256), NTHR, 0, stream>>>(fh, fc, bh, bc, Uf, Ub, zx2, hring, claim, sflag, out);
}